// Round 2
// baseline (10998.917 us; speedup 1.0000x reference)
//
#include <hip/hip_runtime.h>
#include <cmath>

#define H_DIM 2048
#define I_DIM 4096
#define N_DIM 16
#define R_DIM 128
#define K_CONV 4
#define L_DIM 8192
#define LC 2048                 // chunk length (rows per pipeline pass)
#define NCHUNK (L_DIM / LC)

// ---------------------------------------------------------------------------
// Generic tiled fp32 GEMM: C[M,N] = A[M,K] @ B[K,N]  (row-major, strided)
// EPI: 0 = none; 1 = softplus(x + bias[col])
// Requires: M % 128 == 0, K % 16 == 0, N % 4 == 0.
// ---------------------------------------------------------------------------
template <int EPI>
__global__ __launch_bounds__(256) void gemm_f32(
    const float* __restrict__ A, int lda,
    const float* __restrict__ B, int ldb,
    float* __restrict__ C, int ldc,
    int M, int N, int Kd,
    const float* __restrict__ bias)
{
    constexpr int BM = 128, BN = 128, BK = 16;
    __shared__ __align__(16) float As[BK][BM + 4];  // As[k][m]
    __shared__ __align__(16) float Bs[BK][BN + 4];  // Bs[k][n]

    const int m0 = blockIdx.y * BM;
    const int n0 = blockIdx.x * BN;
    const int tid = threadIdx.x;
    const int ty = tid >> 4;   // 0..15
    const int tx = tid & 15;   // 0..15

    const int arow0 = tid >> 2;        // 0..63
    const int ac4   = (tid & 3) * 4;   // 0,4,8,12
    const int brow0 = tid >> 5;        // 0..7
    const int bc4   = (tid & 31) * 4;  // 0..124

    float acc[8][8];
#pragma unroll
    for (int mm = 0; mm < 8; ++mm)
#pragma unroll
        for (int nn = 0; nn < 8; ++nn) acc[mm][nn] = 0.f;

    const float4 z4 = {0.f, 0.f, 0.f, 0.f};

    for (int k0 = 0; k0 < Kd; k0 += BK) {
        float4 a0 = *(const float4*)(A + (size_t)(m0 + arow0) * lda + k0 + ac4);
        float4 a1 = *(const float4*)(A + (size_t)(m0 + arow0 + 64) * lda + k0 + ac4);
        const int bcol = n0 + bc4;
        const bool bok = (bcol < N);
        float4 b0 = bok ? *(const float4*)(B + (size_t)(k0 + brow0) * ldb + bcol) : z4;
        float4 b1 = bok ? *(const float4*)(B + (size_t)(k0 + brow0 + 8) * ldb + bcol) : z4;

        __syncthreads();
        As[ac4 + 0][arow0] = a0.x;
        As[ac4 + 1][arow0] = a0.y;
        As[ac4 + 2][arow0] = a0.z;
        As[ac4 + 3][arow0] = a0.w;
        As[ac4 + 0][arow0 + 64] = a1.x;
        As[ac4 + 1][arow0 + 64] = a1.y;
        As[ac4 + 2][arow0 + 64] = a1.z;
        As[ac4 + 3][arow0 + 64] = a1.w;
        *(float4*)&Bs[brow0][bc4] = b0;
        *(float4*)&Bs[brow0 + 8][bc4] = b1;
        __syncthreads();

#pragma unroll
        for (int kk = 0; kk < BK; ++kk) {
            float4 av0 = *(const float4*)&As[kk][ty * 8];
            float4 av1 = *(const float4*)&As[kk][ty * 8 + 4];
            float4 bv0 = *(const float4*)&Bs[kk][tx * 8];
            float4 bv1 = *(const float4*)&Bs[kk][tx * 8 + 4];
            float a[8] = {av0.x, av0.y, av0.z, av0.w, av1.x, av1.y, av1.z, av1.w};
            float b[8] = {bv0.x, bv0.y, bv0.z, bv0.w, bv1.x, bv1.y, bv1.z, bv1.w};
#pragma unroll
            for (int mm = 0; mm < 8; ++mm)
#pragma unroll
                for (int nn = 0; nn < 8; ++nn)
                    acc[mm][nn] = fmaf(a[mm], b[nn], acc[mm][nn]);
        }
    }

#pragma unroll
    for (int mm = 0; mm < 8; ++mm) {
        const int row = m0 + ty * 8 + mm;
        float* Crow = C + (size_t)row * ldc + n0 + tx * 8;
#pragma unroll
        for (int nn = 0; nn < 8; ++nn) {
            const int col = n0 + tx * 8 + nn;
            if (col < N) {
                float v = acc[mm][nn];
                if (EPI == 1) {
                    v += bias[col];
                    v = (v > 20.f) ? v : log1pf(expf(v));
                }
                Crow[nn] = v;
            }
        }
    }
}

// ---------------------------------------------------------------------------
// Save last 3 x-pre rows of this chunk (cols 0..I of proj, stride 2I) into
// xtail (3 x I) for the next chunk's causal conv window.
// ---------------------------------------------------------------------------
__global__ __launch_bounds__(256) void save_tail_kernel(
    const float* __restrict__ proj, float* __restrict__ xtail)
{
    const int idx = blockIdx.x * 256 + threadIdx.x;  // 3*I threads
    if (idx >= 3 * I_DIM) return;
    const int r = idx >> 12;            // 0..2
    const int i = idx & (I_DIM - 1);
    xtail[idx] = proj[(size_t)(LC - 3 + r) * (2 * I_DIM) + i];
}

// ---------------------------------------------------------------------------
// Causal depthwise conv (K=4) + bias + silu over one chunk.
// x_pre = proj[:, :I] (row stride 2I); history rows from xtail (prev chunk)
// or zero if first chunk.
// ---------------------------------------------------------------------------
__global__ __launch_bounds__(256) void conv_silu_kernel(
    const float* __restrict__ proj,
    const float* __restrict__ xtail,
    const float* __restrict__ w,   // I x 4
    const float* __restrict__ b,   // I
    float* __restrict__ xconv,     // LC x I
    int first)
{
    const int total = LC * I_DIM;
    const int stride = gridDim.x * blockDim.x;
    for (int idx = blockIdx.x * blockDim.x + threadIdx.x; idx < total; idx += stride) {
        const int t = idx >> 12;
        const int i = idx & (I_DIM - 1);
        float s = b[i];
#pragma unroll
        for (int k = 0; k < 4; ++k) {
            const int tt = t - 3 + k;
            float xv;
            if (tt >= 0)          xv = proj[(size_t)tt * (2 * I_DIM) + i];
            else if (!first)      xv = xtail[(size_t)(tt + 3) * I_DIM + i];
            else                  xv = 0.f;
            s = fmaf(w[i * 4 + k], xv, s);
        }
        xconv[idx] = s / (1.f + expf(-s));
    }
}

// ---------------------------------------------------------------------------
// Sequential selective scan over one chunk. One lane per (i, n).
// delta strided in proj[:, :I] (ld 2I); gate = proj[:, I:] (ld 2I).
// u from xc; z = (y + u*D)*silu(gate) written over xc. h carried in hstate.
// ---------------------------------------------------------------------------
__global__ __launch_bounds__(256) void scan_kernel(
    const float* __restrict__ delta,  // ld 2I
    const float* __restrict__ gate,   // ld 2I
    const float* __restrict__ ssm,    // LC x 160 (B at 128, C at 144)
    float* __restrict__ xc,           // LC x I (in: u, out: z)
    const float* __restrict__ A_log,  // I x N
    const float* __restrict__ Dp,     // I
    float* __restrict__ hstate,       // I x N
    int first)
{
    const int tid = threadIdx.x;
    const int n = tid & 15;
    const int il = tid >> 4;
    const int i = blockIdx.x * 16 + il;

    const float Ai = -expf(A_log[(size_t)i * N_DIM + n]);
    const float Di = Dp[i];

    float h = first ? 0.f : hstate[(size_t)i * N_DIM + n];

    float d = delta[i];
    float u = xc[i];
    float g = gate[i];
    float Bt = ssm[128 + n];
    float Ct = ssm[144 + n];

    for (int t = 0; t < LC; ++t) {
        float dn = 0.f, un = 0.f, gn = 0.f, Bn = 0.f, Cn = 0.f;
        if (t + 1 < LC) {
            const size_t r2 = (size_t)(t + 1) * (2 * I_DIM);
            const size_t r1 = (size_t)(t + 1) * I_DIM;
            dn = delta[r2 + i];
            un = xc[r1 + i];
            gn = gate[r2 + i];
            Bn = ssm[(t + 1) * 160 + 128 + n];
            Cn = ssm[(t + 1) * 160 + 144 + n];
        }

        const float e = expf(d * Ai);
        h = fmaf(h, e, (d * u) * Bt);
        float p = h * Ct;
        p += __shfl_xor(p, 1);
        p += __shfl_xor(p, 2);
        p += __shfl_xor(p, 4);
        p += __shfl_xor(p, 8);
        if (n == 0) {
            const float sg = g / (1.f + expf(-g));
            xc[(size_t)t * I_DIM + i] = (p + u * Di) * sg;
        }

        d = dn; u = un; g = gn; Bt = Bn; Ct = Cn;
    }

    hstate[(size_t)i * N_DIM + n] = h;
}

// ---------------------------------------------------------------------------
extern "C" void kernel_launch(void* const* d_in, const int* in_sizes, int n_in,
                              void* d_out, int out_size, void* d_ws, size_t ws_size,
                              hipStream_t stream)
{
    const float* hs      = (const float*)d_in[0];  // L x H
    const float* W_in    = (const float*)d_in[1];  // H x 2I
    const float* conv_w  = (const float*)d_in[2];  // I x 4
    const float* conv_b  = (const float*)d_in[3];  // I
    const float* W_x     = (const float*)d_in[4];  // I x 160
    const float* W_dt    = (const float*)d_in[5];  // 128 x I
    const float* dt_bias = (const float*)d_in[6];  // I
    const float* A_log   = (const float*)d_in[7];  // I x N
    const float* Dp      = (const float*)d_in[8];  // I
    const float* W_out   = (const float*)d_in[9];  // I x H
    float* out = (float*)d_out;

    // Workspace layout (~98 MB total):
    float* ws     = (float*)d_ws;
    float* proj   = ws;                                    // LC * 2I
    float* xconv  = proj + (size_t)LC * 2 * I_DIM;         // LC * I
    float* ssm    = xconv + (size_t)LC * I_DIM;            // LC * 160
    float* xtail  = ssm + (size_t)LC * 160;                // 3 * I
    float* hstate = xtail + (size_t)3 * I_DIM;             // I * N

    const dim3 blk(256);

    for (int c = 0; c < NCHUNK; ++c) {
        const int t0 = c * LC;
        const int first = (c == 0) ? 1 : 0;
        const float* hs_c = hs + (size_t)t0 * H_DIM;
        float* out_c = out + (size_t)t0 * H_DIM;

        // 1) proj = hs_c @ W_in   (LC x 2I)
        gemm_f32<0><<<dim3(2 * I_DIM / 128, LC / 128), blk, 0, stream>>>(
            hs_c, H_DIM, W_in, 2 * I_DIM, proj, 2 * I_DIM, LC, 2 * I_DIM, H_DIM, nullptr);

        // 2) xconv = silu(dwconv(x_pre) + b)
        conv_silu_kernel<<<dim3(4096), blk, 0, stream>>>(
            proj, xtail, conv_w, conv_b, xconv, first);

        // 3) save last-3 x_pre rows for next chunk (before delta overwrites)
        save_tail_kernel<<<dim3((3 * I_DIM + 255) / 256), blk, 0, stream>>>(proj, xtail);

        // 4) ssm = xconv @ W_x  (LC x 160)
        gemm_f32<0><<<dim3(2, LC / 128), blk, 0, stream>>>(
            xconv, I_DIM, W_x, R_DIM + 2 * N_DIM, ssm, R_DIM + 2 * N_DIM,
            LC, R_DIM + 2 * N_DIM, I_DIM, nullptr);

        // 5) delta = softplus(ssm[:, :R] @ W_dt + dt_bias) -> proj[:, :I] (strided)
        gemm_f32<1><<<dim3(I_DIM / 128, LC / 128), blk, 0, stream>>>(
            ssm, R_DIM + 2 * N_DIM, W_dt, I_DIM, proj, 2 * I_DIM,
            LC, I_DIM, R_DIM, dt_bias);

        // 6) scan + fused (y + u*D) * silu(gate) -> xconv (in place)
        scan_kernel<<<dim3(I_DIM / 16), blk, 0, stream>>>(
            proj, proj + I_DIM, ssm, xconv, A_log, Dp, hstate, first);

        // 7) out_c = z @ W_out  (LC x H)
        gemm_f32<0><<<dim3(H_DIM / 128, LC / 128), blk, 0, stream>>>(
            xconv, I_DIM, W_out, H_DIM, out_c, H_DIM, LC, H_DIM, I_DIM, nullptr);
    }
}

// Round 3
// 7595.975 us; speedup vs baseline: 1.4480x; 1.4480x over previous
//
#include <hip/hip_runtime.h>
#include <cmath>

#define H_DIM 2048
#define I_DIM 4096
#define N_DIM 16
#define R_DIM 128
#define K_CONV 4
#define L_DIM 8192
#define LC 2048                 // chunk length
#define NCHUNK (L_DIM / LC)
#define SEG 32                  // scan segments per chunk
#define TSEG (LC / SEG)         // 64 steps per segment
#define IN_DIM (I_DIM * N_DIM)  // 65536 recurrences

// ---------------------------------------------------------------------------
// Generic tiled fp32 GEMM: C[M,N] (+)= A[M,K] @ B[K,N]  (row-major, strided)
// EPI: 0 = none; 1 = softplus(x + bias[col]).  ATOMIC: atomicAdd epilogue
// (split-K over blockIdx.z, K range [z*ksplit, (z+1)*ksplit)).
// Requires: M % 128 == 0, K % 16 == 0, N % 4 == 0.
// ---------------------------------------------------------------------------
template <int EPI, bool ATOMIC>
__global__ __launch_bounds__(256) void gemm_f32(
    const float* __restrict__ A, int lda,
    const float* __restrict__ B, int ldb,
    float* __restrict__ C, int ldc,
    int M, int N, int Kd, int ksplit,
    const float* __restrict__ bias)
{
    constexpr int BM = 128, BN = 128, BK = 16;
    __shared__ __align__(16) float As[BK][BM + 4];  // As[k][m]
    __shared__ __align__(16) float Bs[BK][BN + 4];  // Bs[k][n]

    const int m0 = blockIdx.y * BM;
    const int n0 = blockIdx.x * BN;
    const int tid = threadIdx.x;
    const int ty = tid >> 4;
    const int tx = tid & 15;

    const int arow0 = tid >> 2;
    const int ac4   = (tid & 3) * 4;
    const int brow0 = tid >> 5;
    const int bc4   = (tid & 31) * 4;

    float acc[8][8];
#pragma unroll
    for (int mm = 0; mm < 8; ++mm)
#pragma unroll
        for (int nn = 0; nn < 8; ++nn) acc[mm][nn] = 0.f;

    const float4 z4 = {0.f, 0.f, 0.f, 0.f};

    const int kbeg = blockIdx.z * ksplit;
    const int kend = (kbeg + ksplit < Kd) ? (kbeg + ksplit) : Kd;

    for (int k0 = kbeg; k0 < kend; k0 += BK) {
        float4 a0 = *(const float4*)(A + (size_t)(m0 + arow0) * lda + k0 + ac4);
        float4 a1 = *(const float4*)(A + (size_t)(m0 + arow0 + 64) * lda + k0 + ac4);
        const int bcol = n0 + bc4;
        const bool bok = (bcol < N);
        float4 b0 = bok ? *(const float4*)(B + (size_t)(k0 + brow0) * ldb + bcol) : z4;
        float4 b1 = bok ? *(const float4*)(B + (size_t)(k0 + brow0 + 8) * ldb + bcol) : z4;

        __syncthreads();
        As[ac4 + 0][arow0] = a0.x;
        As[ac4 + 1][arow0] = a0.y;
        As[ac4 + 2][arow0] = a0.z;
        As[ac4 + 3][arow0] = a0.w;
        As[ac4 + 0][arow0 + 64] = a1.x;
        As[ac4 + 1][arow0 + 64] = a1.y;
        As[ac4 + 2][arow0 + 64] = a1.z;
        As[ac4 + 3][arow0 + 64] = a1.w;
        *(float4*)&Bs[brow0][bc4] = b0;
        *(float4*)&Bs[brow0 + 8][bc4] = b1;
        __syncthreads();

#pragma unroll
        for (int kk = 0; kk < BK; ++kk) {
            float4 av0 = *(const float4*)&As[kk][ty * 8];
            float4 av1 = *(const float4*)&As[kk][ty * 8 + 4];
            float4 bv0 = *(const float4*)&Bs[kk][tx * 8];
            float4 bv1 = *(const float4*)&Bs[kk][tx * 8 + 4];
            float a[8] = {av0.x, av0.y, av0.z, av0.w, av1.x, av1.y, av1.z, av1.w};
            float b[8] = {bv0.x, bv0.y, bv0.z, bv0.w, bv1.x, bv1.y, bv1.z, bv1.w};
#pragma unroll
            for (int mm = 0; mm < 8; ++mm)
#pragma unroll
                for (int nn = 0; nn < 8; ++nn)
                    acc[mm][nn] = fmaf(a[mm], b[nn], acc[mm][nn]);
        }
    }

#pragma unroll
    for (int mm = 0; mm < 8; ++mm) {
        const int row = m0 + ty * 8 + mm;
        float* Crow = C + (size_t)row * ldc + n0 + tx * 8;
#pragma unroll
        for (int nn = 0; nn < 8; ++nn) {
            const int col = n0 + tx * 8 + nn;
            if (col < N) {
                float v = acc[mm][nn];
                if (EPI == 1) {
                    v += bias[col];
                    v = (v > 20.f) ? v : log1pf(expf(v));
                }
                if (ATOMIC) atomicAdd(&Crow[nn], v);
                else        Crow[nn] = v;
            }
        }
    }
}

__global__ __launch_bounds__(256) void zero_kernel(float* __restrict__ p, int n)
{
    const int idx = blockIdx.x * 256 + threadIdx.x;
    if (idx < n) p[idx] = 0.f;
}

// ---------------------------------------------------------------------------
// Save last 3 x-pre rows (cols 0..I of proj, stride 2I) for next chunk's conv.
// ---------------------------------------------------------------------------
__global__ __launch_bounds__(256) void save_tail_kernel(
    const float* __restrict__ proj, float* __restrict__ xtail)
{
    const int idx = blockIdx.x * 256 + threadIdx.x;
    if (idx >= 3 * I_DIM) return;
    const int r = idx >> 12;
    const int i = idx & (I_DIM - 1);
    xtail[idx] = proj[(size_t)(LC - 3 + r) * (2 * I_DIM) + i];
}

// ---------------------------------------------------------------------------
// Causal depthwise conv (K=4) + bias + silu over one chunk.
// ---------------------------------------------------------------------------
__global__ __launch_bounds__(256) void conv_silu_kernel(
    const float* __restrict__ proj,
    const float* __restrict__ xtail,
    const float* __restrict__ w,
    const float* __restrict__ b,
    float* __restrict__ xconv,
    int first)
{
    const int total = LC * I_DIM;
    const int stride = gridDim.x * blockDim.x;
    for (int idx = blockIdx.x * blockDim.x + threadIdx.x; idx < total; idx += stride) {
        const int t = idx >> 12;
        const int i = idx & (I_DIM - 1);
        float s = b[i];
#pragma unroll
        for (int k = 0; k < 4; ++k) {
            const int tt = t - 3 + k;
            float xv;
            if (tt >= 0)          xv = proj[(size_t)tt * (2 * I_DIM) + i];
            else if (!first)      xv = xtail[(size_t)(tt + 3) * I_DIM + i];
            else                  xv = 0.f;
            s = fmaf(w[i * 4 + k], xv, s);
        }
        xconv[idx] = s / (1.f + expf(-s));
    }
}

// ---------------------------------------------------------------------------
// Segment-parallel scan. Phase 1: per-segment (prod a, local h_end) from h=0.
// ---------------------------------------------------------------------------
__global__ __launch_bounds__(256) void scan_part1(
    const float* __restrict__ delta,  // ld 2I
    const float* __restrict__ ssm,    // LC x 160, B at 128
    const float* __restrict__ xc,     // LC x I (u)
    const float* __restrict__ A_log,
    float* __restrict__ aprod,        // [SEG][I][N]
    float* __restrict__ hend)         // [SEG][I][N]
{
    const int tid = threadIdx.x;
    const int n = tid & 15;
    const int il = tid >> 4;
    const int i = blockIdx.x * 16 + il;
    const int seg = blockIdx.y;

    const float Ai = -expf(A_log[(size_t)i * N_DIM + n]);
    float h = 0.f, ap = 1.f;
    const int t0 = seg * TSEG;
#pragma unroll 4
    for (int t = t0; t < t0 + TSEG; ++t) {
        const float d  = delta[(size_t)t * (2 * I_DIM) + i];
        const float u  = xc[(size_t)t * I_DIM + i];
        const float Bt = ssm[t * 160 + 128 + n];
        const float a  = expf(d * Ai);
        h = fmaf(h, a, (d * u) * Bt);
        ap *= a;
    }
    const int idx = seg * IN_DIM + i * N_DIM + n;
    aprod[idx] = ap;
    hend[idx]  = h;
}

// Phase 2: chain segment summaries; hend[] becomes h_start[] in place.
__global__ __launch_bounds__(256) void scan_part2(
    const float* __restrict__ aprod,
    float* __restrict__ hend,         // in: local h_end; out: h_start
    float* __restrict__ hstate,       // I x N carry across chunks
    int first)
{
    const int gid = blockIdx.x * 256 + threadIdx.x;  // == i*N + n
    float h = first ? 0.f : hstate[gid];
    for (int s = 0; s < SEG; ++s) {
        const int idx = s * IN_DIM + gid;
        const float ap = aprod[idx];
        const float he = hend[idx];
        hend[idx] = h;                 // h_start for segment s
        h = fmaf(ap, h, he);
    }
    hstate[gid] = h;
}

// Phase 3: re-run each segment from exact h_start; emit z over xc.
__global__ __launch_bounds__(256) void scan_part3(
    const float* __restrict__ delta,
    const float* __restrict__ gate,
    const float* __restrict__ ssm,
    float* __restrict__ xc,           // in: u, out: z
    const float* __restrict__ A_log,
    const float* __restrict__ Dp,
    const float* __restrict__ hstart) // [SEG][I][N]
{
    const int tid = threadIdx.x;
    const int n = tid & 15;
    const int il = tid >> 4;
    const int i = blockIdx.x * 16 + il;
    const int seg = blockIdx.y;

    const float Ai = -expf(A_log[(size_t)i * N_DIM + n]);
    const float Di = Dp[i];
    float h = hstart[seg * IN_DIM + i * N_DIM + n];
    const int t0 = seg * TSEG;
    for (int t = t0; t < t0 + TSEG; ++t) {
        const float d  = delta[(size_t)t * (2 * I_DIM) + i];
        const float u  = xc[(size_t)t * I_DIM + i];
        const float Bt = ssm[t * 160 + 128 + n];
        const float Ct = ssm[t * 160 + 144 + n];
        const float a  = expf(d * Ai);
        h = fmaf(h, a, (d * u) * Bt);
        float p = h * Ct;
        p += __shfl_xor(p, 1);
        p += __shfl_xor(p, 2);
        p += __shfl_xor(p, 4);
        p += __shfl_xor(p, 8);
        if (n == 0) {
            const float g  = gate[(size_t)t * (2 * I_DIM) + i];
            const float sg = g / (1.f + expf(-g));
            xc[(size_t)t * I_DIM + i] = (p + u * Di) * sg;
        }
    }
}

// ---------------------------------------------------------------------------
extern "C" void kernel_launch(void* const* d_in, const int* in_sizes, int n_in,
                              void* d_out, int out_size, void* d_ws, size_t ws_size,
                              hipStream_t stream)
{
    const float* hs      = (const float*)d_in[0];
    const float* W_in    = (const float*)d_in[1];
    const float* conv_w  = (const float*)d_in[2];
    const float* conv_b  = (const float*)d_in[3];
    const float* W_x     = (const float*)d_in[4];
    const float* W_dt    = (const float*)d_in[5];
    const float* dt_bias = (const float*)d_in[6];
    const float* A_log   = (const float*)d_in[7];
    const float* Dp      = (const float*)d_in[8];
    const float* W_out   = (const float*)d_in[9];
    float* out = (float*)d_out;

    float* ws     = (float*)d_ws;
    float* proj   = ws;                                    // LC * 2I (64 MB)
    float* xconv  = proj + (size_t)LC * 2 * I_DIM;         // LC * I  (32 MB)
    float* ssm    = xconv + (size_t)LC * I_DIM;            // LC * 160
    float* xtail  = ssm + (size_t)LC * 160;                // 3 * I
    float* hstate = xtail + (size_t)3 * I_DIM;             // I * N

    const dim3 blk(256);
    const int NSSM = R_DIM + 2 * N_DIM;  // 160

    for (int c = 0; c < NCHUNK; ++c) {
        const int t0 = c * LC;
        const int first = (c == 0) ? 1 : 0;
        const float* hs_c = hs + (size_t)t0 * H_DIM;
        float* out_c = out + (size_t)t0 * H_DIM;
        // Scan scratch lives in this chunk's (not yet written) output region:
        // LC*H = 4,194,304 floats >= 2 * SEG*I*N = 4,194,304. Exact fit.
        float* aprod = out_c;
        float* hend  = out_c + (size_t)SEG * IN_DIM;

        // 1) proj = hs_c @ W_in
        gemm_f32<0, false><<<dim3(2 * I_DIM / 128, LC / 128, 1), blk, 0, stream>>>(
            hs_c, H_DIM, W_in, 2 * I_DIM, proj, 2 * I_DIM, LC, 2 * I_DIM,
            H_DIM, H_DIM, nullptr);

        // 2) xconv = silu(dwconv(x_pre) + b)
        conv_silu_kernel<<<dim3(4096), blk, 0, stream>>>(
            proj, xtail, conv_w, conv_b, xconv, first);

        // 3) save conv tail for next chunk (before delta overwrites x-half)
        save_tail_kernel<<<dim3((3 * I_DIM + 255) / 256), blk, 0, stream>>>(proj, xtail);

        // 4) ssm = xconv @ W_x  (split-K x8, atomic accumulate)
        zero_kernel<<<dim3((LC * NSSM + 255) / 256), blk, 0, stream>>>(ssm, LC * NSSM);
        gemm_f32<0, true><<<dim3(2, LC / 128, 8), blk, 0, stream>>>(
            xconv, I_DIM, W_x, NSSM, ssm, NSSM, LC, NSSM,
            I_DIM, I_DIM / 8, nullptr);

        // 5) delta = softplus(ssm[:, :R] @ W_dt + dt_bias) -> proj[:, :I]
        gemm_f32<1, false><<<dim3(I_DIM / 128, LC / 128, 1), blk, 0, stream>>>(
            ssm, NSSM, W_dt, I_DIM, proj, 2 * I_DIM, LC, I_DIM,
            R_DIM, R_DIM, dt_bias);

        // 6) segment-parallel scan; z written over xconv
        scan_part1<<<dim3(I_DIM / 16, SEG), blk, 0, stream>>>(
            proj, ssm, xconv, A_log, aprod, hend);
        scan_part2<<<dim3(IN_DIM / 256), blk, 0, stream>>>(
            aprod, hend, hstate, first);
        scan_part3<<<dim3(I_DIM / 16, SEG), blk, 0, stream>>>(
            proj, proj + I_DIM, ssm, xconv, A_log, Dp, hend);

        // 7) out_c = z @ W_out  (overwrites the scan scratch)
        gemm_f32<0, false><<<dim3(H_DIM / 128, LC / 128, 1), blk, 0, stream>>>(
            xconv, I_DIM, W_out, H_DIM, out_c, H_DIM, LC, H_DIM,
            I_DIM, I_DIM, nullptr);
    }
}

// Round 4
// 4197.551 us; speedup vs baseline: 2.6203x; 1.8096x over previous
//
#include <hip/hip_runtime.h>
#include <cmath>

#define H_DIM 2048
#define I_DIM 4096
#define N_DIM 16
#define R_DIM 128
#define K_CONV 4
#define L_DIM 8192
#define LC 2048                 // chunk length
#define NCHUNK (L_DIM / LC)
#define SEG 32                  // scan segments per chunk
#define TSEG (LC / SEG)         // 64 steps per segment
#define IN_DIM (I_DIM * N_DIM)  // 65536 recurrences

typedef _Float16 f16x8 __attribute__((ext_vector_type(8)));
typedef float    f32x4 __attribute__((ext_vector_type(4)));

// LDS address helper: [row][k] f16 tiles, 32 k per row, 8-f16 chunks with
// XOR swizzle to spread banks. Returns element offset.
__device__ __forceinline__ int a16(int row, int chunk) {
    return row * 32 + (((chunk ^ ((row + (row >> 2)) & 3)) & 3) << 3);
}

// ---------------------------------------------------------------------------
// Split-fp16 MFMA GEMM: C[M,N] = A[M,K] @ B[K,N] (row-major, strided).
// Each fp32 value is split hi+lo fp16; product via 3 MFMAs (hh + hl + lh).
// EPI: 0 none; 1 softplus(x + bias[col]).
// Requires M%128==0, N%128==0, K%32==0.
// ---------------------------------------------------------------------------
template <int EPI>
__global__ __launch_bounds__(256) void gemm_f16s(
    const float* __restrict__ A, int lda,
    const float* __restrict__ B, int ldb,
    float* __restrict__ C, int ldc,
    int M, int N, int Kd,
    const float* __restrict__ bias)
{
    __shared__ _Float16 Ah[128 * 32];
    __shared__ _Float16 Al[128 * 32];
    __shared__ _Float16 Bh[128 * 32];   // n-major: [n][k]
    __shared__ _Float16 Bl[128 * 32];
    __shared__ float Braw[32][132];     // fp32 staging for B transpose

    const int tid = threadIdx.x;
    const int m0 = blockIdx.y * 128;
    const int n0 = blockIdx.x * 128;

    // staging coords
    const int arow = tid >> 1;          // 0..127
    const int kb   = (tid & 1) << 4;    // 0 or 16
    const int brow = tid >> 3;          // 0..31
    const int bc   = (tid & 7) << 4;    // 0..112
    const int bn   = tid >> 1;          // 0..127
    const int khh  = tid & 1;           // 0/1

    // wave/fragment coords
    const int l  = tid & 63;
    const int w  = tid >> 6;
    const int wm = w & 1, wn = w >> 1;
    const int lr = l & 15, lg = l >> 4;

    f32x4 acc[4][4];
#pragma unroll
    for (int a = 0; a < 4; ++a)
#pragma unroll
        for (int b = 0; b < 4; ++b) acc[a][b] = (f32x4){0.f, 0.f, 0.f, 0.f};

    for (int k0 = 0; k0 < Kd; k0 += 32) {
        // ---- stage A (direct) and B (raw fp32) ----
        {
            const float* Ap = A + (size_t)(m0 + arow) * lda + k0 + kb;
            float x[16];
            *(float4*)&x[0]  = *(const float4*)(Ap + 0);
            *(float4*)&x[4]  = *(const float4*)(Ap + 4);
            *(float4*)&x[8]  = *(const float4*)(Ap + 8);
            *(float4*)&x[12] = *(const float4*)(Ap + 12);
#pragma unroll
            for (int c2 = 0; c2 < 2; ++c2) {
                f16x8 vh, vl;
#pragma unroll
                for (int j = 0; j < 8; ++j) {
                    const float xv = x[c2 * 8 + j];
                    const _Float16 h = (_Float16)xv;
                    vh[j] = h;
                    vl[j] = (_Float16)(xv - (float)h);
                }
                const int off = a16(arow, (kb >> 3) + c2);
                *reinterpret_cast<f16x8*>(&Ah[off]) = vh;
                *reinterpret_cast<f16x8*>(&Al[off]) = vl;
            }
            const float* Bp = B + (size_t)(k0 + brow) * ldb + n0 + bc;
#pragma unroll
            for (int q = 0; q < 4; ++q)
                *(float4*)&Braw[brow][bc + q * 4] = *(const float4*)(Bp + q * 4);
        }
        __syncthreads();

        // ---- split B: read fp32 columns, write n-major hi/lo ----
#pragma unroll
        for (int c2 = 0; c2 < 2; ++c2) {
            f16x8 vh, vl;
#pragma unroll
            for (int j = 0; j < 8; ++j) {
                const float xv = Braw[khh * 16 + c2 * 8 + j][bn];
                const _Float16 h = (_Float16)xv;
                vh[j] = h;
                vl[j] = (_Float16)(xv - (float)h);
            }
            const int off = a16(bn, khh * 2 + c2);
            *reinterpret_cast<f16x8*>(&Bh[off]) = vh;
            *reinterpret_cast<f16x8*>(&Bl[off]) = vl;
        }
        __syncthreads();

        // ---- fragments + MFMA ----
        f16x8 fah[4], fal[4], fbh[4], fbl[4];
#pragma unroll
        for (int t = 0; t < 4; ++t) {
            const int ra = wm * 64 + t * 16 + lr;
            const int oa = a16(ra, lg);
            fah[t] = *reinterpret_cast<f16x8*>(&Ah[oa]);
            fal[t] = *reinterpret_cast<f16x8*>(&Al[oa]);
            const int rb = wn * 64 + t * 16 + lr;
            const int ob = a16(rb, lg);
            fbh[t] = *reinterpret_cast<f16x8*>(&Bh[ob]);
            fbl[t] = *reinterpret_cast<f16x8*>(&Bl[ob]);
        }
#pragma unroll
        for (int mt = 0; mt < 4; ++mt)
#pragma unroll
            for (int nt = 0; nt < 4; ++nt) {
                acc[mt][nt] = __builtin_amdgcn_mfma_f32_16x16x32_f16(
                    fah[mt], fbh[nt], acc[mt][nt], 0, 0, 0);
                acc[mt][nt] = __builtin_amdgcn_mfma_f32_16x16x32_f16(
                    fah[mt], fbl[nt], acc[mt][nt], 0, 0, 0);
                acc[mt][nt] = __builtin_amdgcn_mfma_f32_16x16x32_f16(
                    fal[mt], fbh[nt], acc[mt][nt], 0, 0, 0);
            }
        __syncthreads();
    }

    // ---- epilogue ----
#pragma unroll
    for (int mt = 0; mt < 4; ++mt) {
        const int row = m0 + wm * 64 + mt * 16 + lg * 4;
#pragma unroll
        for (int nt = 0; nt < 4; ++nt) {
            const int col = n0 + wn * 64 + nt * 16 + lr;
#pragma unroll
            for (int j = 0; j < 4; ++j) {
                float v = acc[mt][nt][j];
                if (EPI == 1) {
                    v += bias[col];
                    v = (v > 20.f) ? v : log1pf(expf(v));
                }
                C[(size_t)(row + j) * ldc + col] = v;
            }
        }
    }
}

// ---------------------------------------------------------------------------
// fp32 tiled GEMM (kept for GEMM2, N=160 with split-K atomics).
// ---------------------------------------------------------------------------
template <int EPI, bool ATOMIC>
__global__ __launch_bounds__(256) void gemm_f32(
    const float* __restrict__ A, int lda,
    const float* __restrict__ B, int ldb,
    float* __restrict__ C, int ldc,
    int M, int N, int Kd, int ksplit,
    const float* __restrict__ bias)
{
    constexpr int BM = 128, BN = 128, BK = 16;
    __shared__ __align__(16) float As[BK][BM + 4];
    __shared__ __align__(16) float Bs[BK][BN + 4];

    const int m0 = blockIdx.y * BM;
    const int n0 = blockIdx.x * BN;
    const int tid = threadIdx.x;
    const int ty = tid >> 4;
    const int tx = tid & 15;

    const int arow0 = tid >> 2;
    const int ac4   = (tid & 3) * 4;
    const int brow0 = tid >> 5;
    const int bc4   = (tid & 31) * 4;

    float acc[8][8];
#pragma unroll
    for (int mm = 0; mm < 8; ++mm)
#pragma unroll
        for (int nn = 0; nn < 8; ++nn) acc[mm][nn] = 0.f;

    const float4 z4 = {0.f, 0.f, 0.f, 0.f};

    const int kbeg = blockIdx.z * ksplit;
    const int kend = (kbeg + ksplit < Kd) ? (kbeg + ksplit) : Kd;

    for (int k0 = kbeg; k0 < kend; k0 += BK) {
        float4 a0 = *(const float4*)(A + (size_t)(m0 + arow0) * lda + k0 + ac4);
        float4 a1 = *(const float4*)(A + (size_t)(m0 + arow0 + 64) * lda + k0 + ac4);
        const int bcol = n0 + bc4;
        const bool bok = (bcol < N);
        float4 b0 = bok ? *(const float4*)(B + (size_t)(k0 + brow0) * ldb + bcol) : z4;
        float4 b1 = bok ? *(const float4*)(B + (size_t)(k0 + brow0 + 8) * ldb + bcol) : z4;

        __syncthreads();
        As[ac4 + 0][arow0] = a0.x;
        As[ac4 + 1][arow0] = a0.y;
        As[ac4 + 2][arow0] = a0.z;
        As[ac4 + 3][arow0] = a0.w;
        As[ac4 + 0][arow0 + 64] = a1.x;
        As[ac4 + 1][arow0 + 64] = a1.y;
        As[ac4 + 2][arow0 + 64] = a1.z;
        As[ac4 + 3][arow0 + 64] = a1.w;
        *(float4*)&Bs[brow0][bc4] = b0;
        *(float4*)&Bs[brow0 + 8][bc4] = b1;
        __syncthreads();

#pragma unroll
        for (int kk = 0; kk < BK; ++kk) {
            float4 av0 = *(const float4*)&As[kk][ty * 8];
            float4 av1 = *(const float4*)&As[kk][ty * 8 + 4];
            float4 bv0 = *(const float4*)&Bs[kk][tx * 8];
            float4 bv1 = *(const float4*)&Bs[kk][tx * 8 + 4];
            float a[8] = {av0.x, av0.y, av0.z, av0.w, av1.x, av1.y, av1.z, av1.w};
            float b[8] = {bv0.x, bv0.y, bv0.z, bv0.w, bv1.x, bv1.y, bv1.z, bv1.w};
#pragma unroll
            for (int mm = 0; mm < 8; ++mm)
#pragma unroll
                for (int nn = 0; nn < 8; ++nn)
                    acc[mm][nn] = fmaf(a[mm], b[nn], acc[mm][nn]);
        }
    }

#pragma unroll
    for (int mm = 0; mm < 8; ++mm) {
        const int row = m0 + ty * 8 + mm;
        float* Crow = C + (size_t)row * ldc + n0 + tx * 8;
#pragma unroll
        for (int nn = 0; nn < 8; ++nn) {
            const int col = n0 + tx * 8 + nn;
            if (col < N) {
                float v = acc[mm][nn];
                if (EPI == 1) {
                    v += bias[col];
                    v = (v > 20.f) ? v : log1pf(expf(v));
                }
                if (ATOMIC) atomicAdd(&Crow[nn], v);
                else        Crow[nn] = v;
            }
        }
    }
}

__global__ __launch_bounds__(256) void zero_kernel(float* __restrict__ p, int n)
{
    const int idx = blockIdx.x * 256 + threadIdx.x;
    if (idx < n) p[idx] = 0.f;
}

__global__ __launch_bounds__(256) void save_tail_kernel(
    const float* __restrict__ proj, float* __restrict__ xtail)
{
    const int idx = blockIdx.x * 256 + threadIdx.x;
    if (idx >= 3 * I_DIM) return;
    const int r = idx >> 12;
    const int i = idx & (I_DIM - 1);
    xtail[idx] = proj[(size_t)(LC - 3 + r) * (2 * I_DIM) + i];
}

__global__ __launch_bounds__(256) void conv_silu_kernel(
    const float* __restrict__ proj,
    const float* __restrict__ xtail,
    const float* __restrict__ w,
    const float* __restrict__ b,
    float* __restrict__ xconv,
    int first)
{
    const int total = LC * I_DIM;
    const int stride = gridDim.x * blockDim.x;
    for (int idx = blockIdx.x * blockDim.x + threadIdx.x; idx < total; idx += stride) {
        const int t = idx >> 12;
        const int i = idx & (I_DIM - 1);
        float s = b[i];
#pragma unroll
        for (int k = 0; k < 4; ++k) {
            const int tt = t - 3 + k;
            float xv;
            if (tt >= 0)          xv = proj[(size_t)tt * (2 * I_DIM) + i];
            else if (!first)      xv = xtail[(size_t)(tt + 3) * I_DIM + i];
            else                  xv = 0.f;
            s = fmaf(w[i * 4 + k], xv, s);
        }
        xconv[idx] = s / (1.f + expf(-s));
    }
}

__global__ __launch_bounds__(256) void scan_part1(
    const float* __restrict__ delta,
    const float* __restrict__ ssm,
    const float* __restrict__ xc,
    const float* __restrict__ A_log,
    float* __restrict__ aprod,
    float* __restrict__ hend)
{
    const int tid = threadIdx.x;
    const int n = tid & 15;
    const int il = tid >> 4;
    const int i = blockIdx.x * 16 + il;
    const int seg = blockIdx.y;

    const float Ai = -expf(A_log[(size_t)i * N_DIM + n]);
    float h = 0.f, ap = 1.f;
    const int t0 = seg * TSEG;
#pragma unroll 4
    for (int t = t0; t < t0 + TSEG; ++t) {
        const float d  = delta[(size_t)t * (2 * I_DIM) + i];
        const float u  = xc[(size_t)t * I_DIM + i];
        const float Bt = ssm[t * 160 + 128 + n];
        const float a  = expf(d * Ai);
        h = fmaf(h, a, (d * u) * Bt);
        ap *= a;
    }
    const int idx = seg * IN_DIM + i * N_DIM + n;
    aprod[idx] = ap;
    hend[idx]  = h;
}

__global__ __launch_bounds__(256) void scan_part2(
    const float* __restrict__ aprod,
    float* __restrict__ hend,
    float* __restrict__ hstate,
    int first)
{
    const int gid = blockIdx.x * 256 + threadIdx.x;
    float h = first ? 0.f : hstate[gid];
    for (int s = 0; s < SEG; ++s) {
        const int idx = s * IN_DIM + gid;
        const float ap = aprod[idx];
        const float he = hend[idx];
        hend[idx] = h;
        h = fmaf(ap, h, he);
    }
    hstate[gid] = h;
}

__global__ __launch_bounds__(256) void scan_part3(
    const float* __restrict__ delta,
    const float* __restrict__ gate,
    const float* __restrict__ ssm,
    float* __restrict__ xc,
    const float* __restrict__ A_log,
    const float* __restrict__ Dp,
    const float* __restrict__ hstart)
{
    const int tid = threadIdx.x;
    const int n = tid & 15;
    const int il = tid >> 4;
    const int i = blockIdx.x * 16 + il;
    const int seg = blockIdx.y;

    const float Ai = -expf(A_log[(size_t)i * N_DIM + n]);
    const float Di = Dp[i];
    float h = hstart[seg * IN_DIM + i * N_DIM + n];
    const int t0 = seg * TSEG;
    for (int t = t0; t < t0 + TSEG; ++t) {
        const float d  = delta[(size_t)t * (2 * I_DIM) + i];
        const float u  = xc[(size_t)t * I_DIM + i];
        const float Bt = ssm[t * 160 + 128 + n];
        const float Ct = ssm[t * 160 + 144 + n];
        const float a  = expf(d * Ai);
        h = fmaf(h, a, (d * u) * Bt);
        float p = h * Ct;
        p += __shfl_xor(p, 1);
        p += __shfl_xor(p, 2);
        p += __shfl_xor(p, 4);
        p += __shfl_xor(p, 8);
        if (n == 0) {
            const float g  = gate[(size_t)t * (2 * I_DIM) + i];
            const float sg = g / (1.f + expf(-g));
            xc[(size_t)t * I_DIM + i] = (p + u * Di) * sg;
        }
    }
}

// ---------------------------------------------------------------------------
extern "C" void kernel_launch(void* const* d_in, const int* in_sizes, int n_in,
                              void* d_out, int out_size, void* d_ws, size_t ws_size,
                              hipStream_t stream)
{
    const float* hs      = (const float*)d_in[0];
    const float* W_in    = (const float*)d_in[1];
    const float* conv_w  = (const float*)d_in[2];
    const float* conv_b  = (const float*)d_in[3];
    const float* W_x     = (const float*)d_in[4];
    const float* W_dt    = (const float*)d_in[5];
    const float* dt_bias = (const float*)d_in[6];
    const float* A_log   = (const float*)d_in[7];
    const float* Dp      = (const float*)d_in[8];
    const float* W_out   = (const float*)d_in[9];
    float* out = (float*)d_out;

    float* ws     = (float*)d_ws;
    float* proj   = ws;                                    // LC * 2I
    float* xconv  = proj + (size_t)LC * 2 * I_DIM;         // LC * I
    float* ssm    = xconv + (size_t)LC * I_DIM;            // LC * 160
    float* xtail  = ssm + (size_t)LC * 160;                // 3 * I
    float* hstate = xtail + (size_t)3 * I_DIM;             // I * N

    const dim3 blk(256);
    const int NSSM = R_DIM + 2 * N_DIM;  // 160

    for (int c = 0; c < NCHUNK; ++c) {
        const int t0 = c * LC;
        const int first = (c == 0) ? 1 : 0;
        const float* hs_c = hs + (size_t)t0 * H_DIM;
        float* out_c = out + (size_t)t0 * H_DIM;
        float* aprod = out_c;                           // scan scratch in out
        float* hend  = out_c + (size_t)SEG * IN_DIM;

        // 1) proj = hs_c @ W_in  (split-fp16 MFMA)
        gemm_f16s<0><<<dim3(2 * I_DIM / 128, LC / 128), blk, 0, stream>>>(
            hs_c, H_DIM, W_in, 2 * I_DIM, proj, 2 * I_DIM,
            LC, 2 * I_DIM, H_DIM, nullptr);

        // 2) xconv = silu(dwconv(x_pre) + b)
        conv_silu_kernel<<<dim3(4096), blk, 0, stream>>>(
            proj, xtail, conv_w, conv_b, xconv, first);

        // 3) save conv tail for next chunk
        save_tail_kernel<<<dim3((3 * I_DIM + 255) / 256), blk, 0, stream>>>(proj, xtail);

        // 4) ssm = xconv @ W_x  (fp32 split-K x8)
        zero_kernel<<<dim3((LC * NSSM + 255) / 256), blk, 0, stream>>>(ssm, LC * NSSM);
        gemm_f32<0, true><<<dim3(2, LC / 128, 8), blk, 0, stream>>>(
            xconv, I_DIM, W_x, NSSM, ssm, NSSM, LC, NSSM,
            I_DIM, I_DIM / 8, nullptr);

        // 5) delta = softplus(ssm[:, :R] @ W_dt + dt_bias) -> proj[:, :I]
        gemm_f16s<1><<<dim3(I_DIM / 128, LC / 128), blk, 0, stream>>>(
            ssm, NSSM, W_dt, I_DIM, proj, 2 * I_DIM,
            LC, I_DIM, R_DIM, dt_bias);

        // 6) segment-parallel scan; z over xconv
        scan_part1<<<dim3(I_DIM / 16, SEG), blk, 0, stream>>>(
            proj, ssm, xconv, A_log, aprod, hend);
        scan_part2<<<dim3(IN_DIM / 256), blk, 0, stream>>>(
            aprod, hend, hstate, first);
        scan_part3<<<dim3(I_DIM / 16, SEG), blk, 0, stream>>>(
            proj, proj + I_DIM, ssm, xconv, A_log, Dp, hend);

        // 7) out_c = z @ W_out  (split-fp16 MFMA)
        gemm_f16s<0><<<dim3(H_DIM / 128, LC / 128), blk, 0, stream>>>(
            xconv, I_DIM, W_out, H_DIM, out_c, H_DIM,
            LC, H_DIM, I_DIM, nullptr);
    }
}